// Round 5
// baseline (2089.102 us; speedup 1.0000x reference)
//
#include <hip/hip_runtime.h>
#include <math.h>

#define H    512
#define H4   2048
#define OPS  12
#define E    112

// ---- workspace float offsets ----
#define WS_EW    16                     // 12*2048: emb @ Wih0^T (per action)
#define WS_GUM   (WS_EW + 12*H4)        // 1344 gumbel noise
#define WS_B0    (WS_GUM + E*OPS)       // bih0+bhh0 (4H)
#define WS_B1    (WS_B0 + H4)           // bih1+bhh1 (4H)
#define WS_G0    (WS_B1 + H4)           // cell-0 gates (4H), incl. B0+EW
#define WS_G1B   (WS_G0 + H4)           // Whh1 @ h1 (4H)
#define WS_G1    (WS_G1B + H4)          // cell-1 summed gates (4H)
#define WS_HM    (WS_G1 + H4)           // controller hidden (H)
#define WS_ST    (WS_HM + H)            // 2 bufs x [h0,h1,c0,c1] x H

__device__ __forceinline__ float sigf(float x) { return 1.f / (1.f + expf(-x)); }

// JAX threefry2x32, key = PRNGKey(42) = (0,42), 20 rounds
__device__ __forceinline__ void threefry_42(unsigned x0, unsigned x1,
                                            unsigned& o0, unsigned& o1) {
  const unsigned k0 = 0u, k1 = 42u;
  const unsigned k2 = k0 ^ k1 ^ 0x1BD11BDAu;
  x0 += k0; x1 += k1;
#define TF_R(rot) { x0 += x1; x1 = (x1 << rot) | (x1 >> (32 - rot)); x1 ^= x0; }
  TF_R(13) TF_R(15) TF_R(26) TF_R(6)
  x0 += k1; x1 += k2 + 1u;
  TF_R(17) TF_R(29) TF_R(16) TF_R(24)
  x0 += k2; x1 += k0 + 2u;
  TF_R(13) TF_R(15) TF_R(26) TF_R(6)
  x0 += k0; x1 += k1 + 3u;
  TF_R(17) TF_R(29) TF_R(16) TF_R(24)
  x0 += k1; x1 += k2 + 4u;
  TF_R(13) TF_R(15) TF_R(26) TF_R(6)
  x0 += k2; x1 += k0 + 5u;
#undef TF_R
  o0 = x0; o1 = x1;
}

__device__ __forceinline__ float bits_to_gumbel(unsigned bits) {
  unsigned fb = (bits >> 9) | 0x3f800000u;
  float u = __uint_as_float(fb) - 1.0f;          // [0,1)
  u = u + 1.17549435e-38f;                       // * (1-tiny) + tiny
  u = fmaxf(1.17549435e-38f, u);
  return -logf(-logf(u));
}

// robust scalar decode: f32 -> int32 -> f64 probing
__device__ __forceinline__ float decode_temp(const void* temp_p) {
  float tf = *(const float*)temp_p;
  float a = fabsf(tf);
  if (a > 1e-6f && a < 1e6f) return tf;
  int ti = *(const int*)temp_p;
  if (ti != 0 && ti > -1000000 && ti < 1000000) return (float)ti;
  double td = *(const double*)temp_p;
  double ad = fabs(td);
  if (ad > 1e-6 && ad < 1e6) return (float)td;
  return 1.0f;
}

// ---------------------------------------------------------------------------
__global__ void k_touch(float* out) {
  int t = blockIdx.x * blockDim.x + threadIdx.x;
  if (t < 3 * E) out[t] = -7777.0f;
}

__global__ void k_diag(float* out, float v) {
  if (threadIdx.x == 0 && blockIdx.x == 0) out[0] = v;
}

__global__ void __launch_bounds__(256)
k_setup(const float* h0_in, const float* c0_in,
        const float* Wih0, const float* bih0, const float* bhh0,
        const float* bih1, const float* bhh1,
        const float* emb, float* ws) {
  int gt = blockIdx.x * blockDim.x + threadIdx.x;
  const int N_EW  = 12 * H4;                 // 24576
  const int N_GUM = N_EW + E * OPS;          // 25920 (1344 gumbels, one thread each)
  const int N_B0  = N_GUM + H4;              // 27968
  const int N_B1  = N_B0 + H4;               // 30016
  const int N_H   = N_B1 + 2 * H;            // 31040
  const int N_C   = N_H + 2 * H;             // 32064
  if (gt < N_EW) {
    int a = gt >> 11, r = gt & (H4 - 1);
    const float* er = emb + a * H;
    const float* wr = Wih0 + (size_t)r * H;
    float acc = 0.f;
    for (int k = 0; k < H; k += 4) {
      float4 e4 = *(const float4*)(er + k);
      float4 w4 = *(const float4*)(wr + k);
      acc += e4.x * w4.x + e4.y * w4.y + e4.z * w4.z + e4.w * w4.w;
    }
    ws[WS_EW + gt] = acc;
  } else if (gt < N_GUM) {
    // JAX partitionable threefry (default True in modern JAX):
    // per flat index t: (y0,y1) = threefry2x32(key, (hi32(t)=0, lo32(t)=t));
    // 32-bit output = y0 ^ y1 (xor-fold of the 64-bit reconstruction)
    int p = gt - N_EW;
    unsigned y0, y1;
    threefry_42(0u, (unsigned)p, y0, y1);
    ws[WS_GUM + p] = bits_to_gumbel(y0 ^ y1);
  } else if (gt < N_B0) {
    int j = gt - N_GUM;
    ws[WS_B0 + j] = bih0[j] + bhh0[j];
  } else if (gt < N_B1) {
    int j = gt - N_B0;
    ws[WS_B1 + j] = bih1[j] + bhh1[j];
  } else if (gt < N_H) {
    int j = gt - N_B1;                       // h0,h1 (buf 0)
    ws[WS_ST + j] = h0_in[j];
  } else if (gt < N_C) {
    int j = gt - N_H;                        // c0,c1 (buf 0)
    ws[WS_ST + 2 * H + j] = c0_in[j];
  }
}

// sampling for logits-step li; every calling WG computes it redundantly and
// bit-identically; bid 0 writes outputs (actions carry a +0.001 marker).
__device__ __forceinline__ int do_sample(int li, const void* temp_p,
                                         const float* cW2, const float* cb2,
                                         const float* ws, float* out,
                                         int tid, int bid, int* s_act) {
  if (tid < 64) {
    float lg[OPS];
#pragma unroll
    for (int o = 0; o < OPS; ++o) lg[o] = 0.f;
#pragma unroll
    for (int jj = 0; jj < 8; ++jj) {
      int j = jj * 64 + tid;
      float hm = ws[WS_HM + j];
      const float* w2r = cW2 + ((size_t)li * H + j) * OPS;
#pragma unroll
      for (int o = 0; o < OPS; ++o) lg[o] += hm * w2r[o];
    }
#pragma unroll
    for (int s = 1; s < 64; s <<= 1) {
#pragma unroll
      for (int o = 0; o < OPS; ++o) lg[o] += __shfl_xor(lg[o], s);
    }
    float invt = 1.f / decode_temp(temp_p);
#pragma unroll
    for (int o = 0; o < OPS; ++o) lg[o] = (lg[o] + cb2[li * OPS + o]) * invt;
    float mx = lg[0];
#pragma unroll
    for (int o = 1; o < OPS; ++o) mx = fmaxf(mx, lg[o]);
    float se = 0.f;
#pragma unroll
    for (int o = 0; o < OPS; ++o) se += expf(lg[o] - mx);
    float logZ = mx + logf(se);
    float best = -1e30f; int act = 0;
#pragma unroll
    for (int o = 0; o < OPS; ++o) {
      float v = lg[o] + ws[WS_GUM + li * OPS + o];
      if (v > best) { best = v; act = o; }
    }
    if (tid == 0) {
      *s_act = act;
      if (bid == 0) {
        float lp = lg[act] - logZ;
        float ent = 0.f;
        for (int o = 0; o < OPS; ++o) {
          float l2 = lg[o] - logZ;
          ent -= expf(l2) * l2;
        }
        out[li]         = (float)act + 0.001f;   // marker: proves our build ran
        out[E + li]     = lp;
        out[2 * E + li] = ent;
      }
    }
  }
  __syncthreads();
  return *s_act;
}

// k1: sample step i-1 (if i>0), then G0 = Whh0@h0 + B0 + EW[a], G1B = Whh1@h1
__global__ void __launch_bounds__(256)
k1_sample_gates(int i, const void* temp_p,
                const float* Whh0, const float* Whh1,
                const float* cW2, const float* cb2,
                float* out, float* ws) {
  __shared__ int s_act;
  int tid = threadIdx.x, bid = blockIdx.x;
  int gt = bid * 256 + tid;
  int p = i & 1;

  int a_prev = -1;
  if (i > 0) {
    a_prev = do_sample(i - 1, temp_p, cW2, cb2, ws, out, tid, bid, &s_act);
  }

  int row = gt >> 3, seg = gt & 7;
  const float* wr;
  const float* hv;
  if (row < H4) { wr = Whh0 + (size_t)row * H;        hv = ws + WS_ST + p * 4 * H; }
  else          { wr = Whh1 + (size_t)(row - H4) * H; hv = ws + WS_ST + p * 4 * H + H; }
  wr += seg * 64; hv += seg * 64;
  float acc = 0.f;
#pragma unroll
  for (int k = 0; k < 64; k += 4) {
    float4 w4 = *(const float4*)(wr + k);
    float4 h4 = *(const float4*)(hv + k);
    acc += w4.x * h4.x + w4.y * h4.y + w4.z * h4.z + w4.w * h4.w;
  }
  acc += __shfl_xor(acc, 1);
  acc += __shfl_xor(acc, 2);
  acc += __shfl_xor(acc, 4);
  if (seg == 0) {
    if (row < H4) {
      float g = acc + ws[WS_B0 + row];
      if (a_prev >= 0) g += ws[WS_EW + a_prev * H4 + row];
      ws[WS_G0 + row] = g;
    } else {
      ws[WS_G1B + (row - H4)] = acc;
    }
  }
}

// k2: cell-0 pointwise (redundant per WG) -> h0n; G1 = Wih1@h0n + G1B + B1
__global__ void __launch_bounds__(256)
k2_cell0_g1(int i, const float* Wih1, float* ws) {
  __shared__ __align__(16) float sh0n[H];
  int tid = threadIdx.x, bid = blockIdx.x;
  int gt = bid * 256 + tid;
  int p = i & 1;
  const float* cst = ws + WS_ST + p * 4 * H + 2 * H;       // c0 (read)
  float* hst_n = ws + WS_ST + (1 - p) * 4 * H;             // h0 (write)
  float* cst_n = ws + WS_ST + (1 - p) * 4 * H + 2 * H;     // c0 (write)

#pragma unroll
  for (int e = 0; e < 2; ++e) {
    int j = tid + e * 256;
    float gi = ws[WS_G0 + j];
    float gf = ws[WS_G0 + H + j];
    float gg = ws[WS_G0 + 2 * H + j];
    float go = ws[WS_G0 + 3 * H + j];
    float cn = sigf(gf) * cst[j] + sigf(gi) * tanhf(gg);
    float hn = sigf(go) * tanhf(cn);
    sh0n[j] = hn;
    if (bid == 0) { cst_n[j] = cn; hst_n[j] = hn; }
  }
  __syncthreads();

  int row = gt >> 3, seg = gt & 7;                          // 64 WGs -> 2048 rows
  const float* wr = Wih1 + (size_t)row * H + seg * 64;
  float acc = 0.f;
#pragma unroll
  for (int k = 0; k < 64; k += 4) {
    float4 w4 = *(const float4*)(wr + k);
    acc += w4.x * sh0n[seg * 64 + k]     + w4.y * sh0n[seg * 64 + k + 1]
         + w4.z * sh0n[seg * 64 + k + 2] + w4.w * sh0n[seg * 64 + k + 3];
  }
  acc += __shfl_xor(acc, 1);
  acc += __shfl_xor(acc, 2);
  acc += __shfl_xor(acc, 4);
  if (seg == 0) {
    ws[WS_G1 + row] = acc + ws[WS_G1B + row] + ws[WS_B1 + row];
  }
}

// k3: cell-1 pointwise (redundant per WG) -> h1n; HM = relu(h1n @ W1[i] + b1)
__global__ void __launch_bounds__(256)
k3_cell1_mlp(int i, const float* cW1, const float* cb1, float* ws) {
  __shared__ __align__(16) float sh1n[H];
  __shared__ float spart[4][4];
  int tid = threadIdx.x, bid = blockIdx.x;
  int p = i & 1;
  const float* cst = ws + WS_ST + p * 4 * H + 3 * H;       // c1 (read)
  float* hst_n = ws + WS_ST + (1 - p) * 4 * H + H;         // h1 (write)
  float* cst_n = ws + WS_ST + (1 - p) * 4 * H + 3 * H;     // c1 (write)

#pragma unroll
  for (int e = 0; e < 2; ++e) {
    int j = tid + e * 256;
    float gi = ws[WS_G1 + j];
    float gf = ws[WS_G1 + H + j];
    float gg = ws[WS_G1 + 2 * H + j];
    float go = ws[WS_G1 + 3 * H + j];
    float cn = sigf(gf) * cst[j] + sigf(gi) * tanhf(gg);
    float hn = sigf(go) * tanhf(cn);
    sh1n[j] = hn;
    if (bid == 0) { cst_n[j] = cn; hst_n[j] = hn; }
  }
  __syncthreads();

  // 4 output columns per WG (128 WGs x 4 = 512)
  int wv = tid >> 6, ln = tid & 63;
  int jl = ln & 3, ks = ln >> 2;
  int jout = bid * 4 + jl;
  const float* w1 = cW1 + (size_t)i * H * H;
  int kbase = wv * 128 + ks * 8;
  float acc = 0.f;
#pragma unroll
  for (int t = 0; t < 8; ++t) {
    int k = kbase + t;
    acc += sh1n[k] * w1[(size_t)k * H + jout];
  }
  acc += __shfl_xor(acc, 4);
  acc += __shfl_xor(acc, 8);
  acc += __shfl_xor(acc, 16);
  acc += __shfl_xor(acc, 32);
  if (ln < 4) spart[wv][ln] = acc;
  __syncthreads();
  if (tid < 4) {
    float s = spart[0][tid] + spart[1][tid] + spart[2][tid] + spart[3][tid];
    s += cb1[(size_t)i * H + bid * 4 + tid];
    ws[WS_HM + bid * 4 + tid] = fmaxf(s, 0.f);
  }
}

// final sampler for step E-1
__global__ void __launch_bounds__(256)
kF_final(const void* temp_p, const float* cW2, const float* cb2,
         float* out, float* ws) {
  __shared__ int s_act;
  do_sample(E - 1, temp_p, cW2, cb2, ws, out, threadIdx.x, blockIdx.x, &s_act);
}

extern "C" void kernel_launch(void* const* d_in, const int* in_sizes, int n_in,
                              void* d_out, int out_size, void* d_ws, size_t ws_size,
                              hipStream_t stream) {
  (void)out_size; (void)ws_size;
  float* out = (float*)d_out;
  float* ws  = (float*)d_ws;

  (void)hipGetLastError();   // drain stale errors so our check is clean

  // ---- input layout self-check ----
  static const long long expect[16] = {
      1, 1024, 1024, 1048576, 1048576, 2048, 2048,
      1048576, 1048576, 2048, 2048, 6144,
      29360128, 57344, 688128, 1344 };
  int bad = -1;
  if (n_in != 16) bad = 99;
  else {
    for (int i = 0; i < 16; ++i)
      if ((long long)in_sizes[i] != expect[i]) { bad = i; break; }
  }

  k_touch<<<2, 256, 0, stream>>>(out);
  if (bad >= 0) {
    k_diag<<<1, 64, 0, stream>>>(out, 80000.0f + (float)bad);
    return;
  }

  const void*  temp_p = d_in[0];
  const float* h0   = (const float*)d_in[1];
  const float* c0   = (const float*)d_in[2];
  const float* Wih0 = (const float*)d_in[3];
  const float* Whh0 = (const float*)d_in[4];
  const float* bih0 = (const float*)d_in[5];
  const float* bhh0 = (const float*)d_in[6];
  const float* Wih1 = (const float*)d_in[7];
  const float* Whh1 = (const float*)d_in[8];
  const float* bih1 = (const float*)d_in[9];
  const float* bhh1 = (const float*)d_in[10];
  const float* emb  = (const float*)d_in[11];
  const float* cW1  = (const float*)d_in[12];
  const float* cb1  = (const float*)d_in[13];
  const float* cW2  = (const float*)d_in[14];
  const float* cb2  = (const float*)d_in[15];

  k_setup<<<128, 256, 0, stream>>>(h0, c0, Wih0, bih0, bhh0, bih1, bhh1, emb, ws);
  for (int i = 0; i < E; ++i) {
    k1_sample_gates<<<128, 256, 0, stream>>>(i, temp_p, Whh0, Whh1, cW2, cb2, out, ws);
    k2_cell0_g1<<<64, 256, 0, stream>>>(i, Wih1, ws);
    k3_cell1_mlp<<<128, 256, 0, stream>>>(i, cW1, cb1, ws);
  }
  kF_final<<<1, 256, 0, stream>>>(temp_p, cW2, cb2, out, ws);

  hipError_t e = hipGetLastError();
  if (e != hipSuccess) {
    k_diag<<<1, 64, 0, stream>>>(out, 90000.0f + (float)(int)e);
  }
}